// Round 1
// baseline (1403.915 us; speedup 1.0000x reference)
//
#include <hip/hip_runtime.h>
#include <hip/hip_bf16.h>
#include <math.h>

// Problem constants (B=2,S=512 -> T=1024)
#define T_    1024
#define H_    2048
#define E_    64
#define I_    1024
#define TOPK  8
#define CAP   1024        // max rows per expert (worst case all tokens)

// GEMM tiling
#define TM    64          // token rows per m-tile
#define TN    128         // output cols per block
#define BK    64          // k-chunk
#define LDK   (BK + 8)    // padded LDS leading dim (16B pad -> 2-way max conflicts)

typedef __attribute__((ext_vector_type(8))) short  short8;
typedef __attribute__((ext_vector_type(8))) __bf16 bf16x8;
typedef __attribute__((ext_vector_type(4))) float  f32x4;

__device__ __forceinline__ unsigned short f2bf(float f) {
  unsigned int u = __float_as_uint(f);
  u += 0x7FFFu + ((u >> 16) & 1u);   // RNE
  return (unsigned short)(u >> 16);
}

__device__ __forceinline__ f32x4 mfma16(short8 a, short8 b, f32x4 c) {
  return __builtin_amdgcn_mfma_f32_16x16x32_bf16(
      __builtin_bit_cast(bf16x8, a), __builtin_bit_cast(bf16x8, b), c, 0, 0, 0);
}

// ---------------------------------------------------------------------------
// Kernel 1: router. One block per token. fp32 logits -> softmax -> top-8.
// Emits top_w (flat [T*K]) and per-expert row lists rows[e][..] of r = t*8+k.
// ---------------------------------------------------------------------------
__global__ __launch_bounds__(256) void router_k(
    const float* __restrict__ x, const float* __restrict__ rw,
    float* __restrict__ topw, int* __restrict__ counts, int* __restrict__ rows)
{
  __shared__ float xs[H_];
  __shared__ float lg[E_];
  const int t   = blockIdx.x;
  const int tid = threadIdx.x;
  const float* xr = x + (size_t)t * H_;
  for (int q = tid; q < H_ / 4; q += 256)
    ((float4*)xs)[q] = ((const float4*)xr)[q];
  __syncthreads();

  const int w = tid >> 6, lane = tid & 63;
  for (int ee = 0; ee < E_ / 4; ++ee) {
    const int e = w * (E_ / 4) + ee;
    const float* wr = rw + (size_t)e * H_;
    float p = 0.f;
    for (int h = lane; h < H_; h += 64) p += xs[h] * wr[h];
    for (int off = 32; off; off >>= 1) p += __shfl_xor(p, off);
    if (lane == 0) lg[e] = p;
  }
  __syncthreads();

  if (w == 0) {
    const float logit = lg[lane];
    float mx = logit;
    for (int off = 32; off; off >>= 1) mx = fmaxf(mx, __shfl_xor(mx, off));
    const float ex = expf(logit - mx);
    float sum = ex;
    for (int off = 32; off; off >>= 1) sum += __shfl_xor(sum, off);
    float p = ex / sum;   // prob for expert=lane
    for (int k = 0; k < TOPK; ++k) {
      float m = p; int mi = lane;
      for (int off = 32; off; off >>= 1) {
        const float om = __shfl_xor(m, off);
        const int   oi = __shfl_xor(mi, off);
        if (om > m || (om == m && oi < mi)) { m = om; mi = oi; }
      }
      if (lane == 0) {
        const int r = t * TOPK + k;
        topw[r] = m;
        const int pos = atomicAdd(&counts[mi], 1);
        rows[mi * CAP + pos] = r;
      }
      if (lane == mi) p = -1.f;
    }
  }
}

// ---------------------------------------------------------------------------
// Kernel 2: gate/up GEMM per expert. grid=(E, I/TN). Loops over m-tiles so
// each expert weight slice is fetched from HBM once. Writes hmid bf16.
// ---------------------------------------------------------------------------
__global__ __launch_bounds__(256) void gateup_k(
    const float* __restrict__ x, const float* __restrict__ wg,
    const float* __restrict__ wu, const float* __restrict__ topw,
    const int* __restrict__ counts, const int* __restrict__ rows,
    unsigned short* __restrict__ hmid)
{
  const int e  = blockIdx.x;
  const int n0 = blockIdx.y * TN;
  const int cnt = counts[e];
  if (cnt == 0) return;
  const int* erows = rows + e * CAP;

  __shared__ __align__(16) unsigned short Xs[TM][LDK];
  __shared__ __align__(16) unsigned short Gs[TN][LDK];
  __shared__ __align__(16) unsigned short Us[TN][LDK];
  __shared__ float cws[TM];
  __shared__ int   ridx[TM];

  const int tid = threadIdx.x;
  const int wid = tid >> 6, lane = tid & 63;
  const int wm = wid >> 1, wn = wid & 1;     // 2x2 waves: 32 rows x 64 cols each

  const float* wgE = wg + (size_t)e * I_ * H_;
  const float* wuE = wu + (size_t)e * I_ * H_;

  for (int m0 = 0; m0 < cnt; m0 += TM) {
    __syncthreads();   // protect cws/ridx from previous tile's epilogue readers
    if (tid < TM) {
      const int mrow = m0 + tid;
      const int r = erows[(mrow < cnt) ? mrow : 0];
      ridx[tid] = r;
      cws[tid]  = (mrow < cnt) ? topw[r] : 0.f;
    }
    f32x4 accg[2][4], accu[2][4];
#pragma unroll
    for (int i = 0; i < 2; ++i)
#pragma unroll
      for (int j = 0; j < 4; ++j)
#pragma unroll
        for (int q = 0; q < 4; ++q) { accg[i][j][q] = 0.f; accu[i][j][q] = 0.f; }

    for (int k0 = 0; k0 < H_; k0 += BK) {
      __syncthreads();
      // X gather: TM x BK fp32 -> bf16 LDS
      for (int q = tid; q < TM * (BK / 4); q += 256) {
        const int m = q >> 4, seg = q & 15;
        const int t = ridx[m] >> 3;
        const float4 v = *(const float4*)(x + (size_t)t * H_ + k0 + seg * 4);
        ushort4 b; b.x = f2bf(v.x); b.y = f2bf(v.y); b.z = f2bf(v.z); b.w = f2bf(v.w);
        *(ushort4*)&Xs[m][seg * 4] = b;
      }
      // Wg/Wu: TN x BK fp32 -> bf16 LDS
      for (int q = tid; q < TN * (BK / 4); q += 256) {
        const int i = q >> 4, seg = q & 15;
        const size_t go = (size_t)(n0 + i) * H_ + k0 + seg * 4;
        const float4 vg = *(const float4*)(wgE + go);
        ushort4 bg; bg.x = f2bf(vg.x); bg.y = f2bf(vg.y); bg.z = f2bf(vg.z); bg.w = f2bf(vg.w);
        *(ushort4*)&Gs[i][seg * 4] = bg;
        const float4 vu = *(const float4*)(wuE + go);
        ushort4 bu; bu.x = f2bf(vu.x); bu.y = f2bf(vu.y); bu.z = f2bf(vu.z); bu.w = f2bf(vu.w);
        *(ushort4*)&Us[i][seg * 4] = bu;
      }
      __syncthreads();
#pragma unroll
      for (int ks = 0; ks < 2; ++ks) {
        const int ko = ks * 32 + (lane >> 4) * 8;
        const short8 a0 = *(const short8*)&Xs[wm * 32 + (lane & 15)][ko];
        const short8 a1 = *(const short8*)&Xs[wm * 32 + 16 + (lane & 15)][ko];
#pragma unroll
        for (int ni = 0; ni < 4; ++ni) {
          const int col = wn * 64 + ni * 16 + (lane & 15);
          const short8 bg = *(const short8*)&Gs[col][ko];
          const short8 bu = *(const short8*)&Us[col][ko];
          accg[0][ni] = mfma16(a0, bg, accg[0][ni]);
          accg[1][ni] = mfma16(a1, bg, accg[1][ni]);
          accu[0][ni] = mfma16(a0, bu, accu[0][ni]);
          accu[1][ni] = mfma16(a1, bu, accu[1][ni]);
        }
      }
    }
    // epilogue: h = silu(g)*u*cw -> bf16 store
#pragma unroll
    for (int mi = 0; mi < 2; ++mi)
#pragma unroll
      for (int ni = 0; ni < 4; ++ni)
#pragma unroll
        for (int j = 0; j < 4; ++j) {
          const int ml = wm * 32 + mi * 16 + (lane >> 4) * 4 + j;
          if (m0 + ml < cnt) {
            const int r = ridx[ml];
            const float g = accg[mi][ni][j], u = accu[mi][ni][j];
            const float h = g / (1.f + __expf(-g)) * u * cws[ml];
            hmid[(size_t)r * I_ + n0 + wn * 64 + ni * 16 + (lane & 15)] = f2bf(h);
          }
        }
  }
}

// ---------------------------------------------------------------------------
// Kernel 3: down GEMM per expert. grid=(E, H/TN). partial[(t,k)][h] unique
// writes (deterministic); atomic fallback adds straight into out.
// ---------------------------------------------------------------------------
__global__ __launch_bounds__(256) void down_k(
    const unsigned short* __restrict__ hmid, const float* __restrict__ wd,
    const int* __restrict__ counts, const int* __restrict__ rows,
    float* __restrict__ outp, const int atomicMode)
{
  const int e  = blockIdx.x;
  const int n0 = blockIdx.y * TN;
  const int cnt = counts[e];
  if (cnt == 0) return;
  const int* erows = rows + e * CAP;

  __shared__ __align__(16) unsigned short As[TM][LDK];
  __shared__ __align__(16) unsigned short Ws[TN][LDK];
  __shared__ int ridx[TM];

  const int tid = threadIdx.x;
  const int wid = tid >> 6, lane = tid & 63;
  const int wm = wid >> 1, wn = wid & 1;

  const float* wdE = wd + (size_t)e * H_ * I_;

  for (int m0 = 0; m0 < cnt; m0 += TM) {
    __syncthreads();
    if (tid < TM) {
      const int mrow = m0 + tid;
      ridx[tid] = erows[(mrow < cnt) ? mrow : 0];
    }
    f32x4 acc[2][4];
#pragma unroll
    for (int i = 0; i < 2; ++i)
#pragma unroll
      for (int j = 0; j < 4; ++j)
#pragma unroll
        for (int q = 0; q < 4; ++q) acc[i][j][q] = 0.f;

    for (int k0 = 0; k0 < I_; k0 += BK) {
      __syncthreads();
      // A: hmid rows (already bf16), 16B chunks
      for (int q = tid; q < TM * (BK / 8); q += 256) {
        const int m = q >> 3, seg = q & 7;
        const int r = ridx[m];
        const uint4 v = *(const uint4*)(hmid + (size_t)r * I_ + k0 + seg * 8);
        *(uint4*)&As[m][seg * 8] = v;
      }
      // B: w_down[e][h][i] fp32 -> bf16
      for (int q = tid; q < TN * (BK / 4); q += 256) {
        const int hh = q >> 4, seg = q & 15;
        const float4 v = *(const float4*)(wdE + (size_t)(n0 + hh) * I_ + k0 + seg * 4);
        ushort4 b; b.x = f2bf(v.x); b.y = f2bf(v.y); b.z = f2bf(v.z); b.w = f2bf(v.w);
        *(ushort4*)&Ws[hh][seg * 4] = b;
      }
      __syncthreads();
#pragma unroll
      for (int ks = 0; ks < 2; ++ks) {
        const int ko = ks * 32 + (lane >> 4) * 8;
        const short8 a0 = *(const short8*)&As[wm * 32 + (lane & 15)][ko];
        const short8 a1 = *(const short8*)&As[wm * 32 + 16 + (lane & 15)][ko];
#pragma unroll
        for (int ni = 0; ni < 4; ++ni) {
          const short8 b = *(const short8*)&Ws[wn * 64 + ni * 16 + (lane & 15)][ko];
          acc[0][ni] = mfma16(a0, b, acc[0][ni]);
          acc[1][ni] = mfma16(a1, b, acc[1][ni]);
        }
      }
    }
#pragma unroll
    for (int mi = 0; mi < 2; ++mi)
#pragma unroll
      for (int ni = 0; ni < 4; ++ni)
#pragma unroll
        for (int j = 0; j < 4; ++j) {
          const int ml = wm * 32 + mi * 16 + (lane >> 4) * 4 + j;
          if (m0 + ml < cnt) {
            const int r = ridx[ml];
            const int col = n0 + wn * 64 + ni * 16 + (lane & 15);
            if (atomicMode) atomicAdd(&outp[(size_t)(r >> 3) * H_ + col], acc[mi][ni][j]);
            else            outp[(size_t)r * H_ + col] = acc[mi][ni][j];
          }
        }
  }
}

// ---------------------------------------------------------------------------
// Kernel 4: combine partials over k=0..7 (deterministic fixed-order sum)
// ---------------------------------------------------------------------------
__global__ __launch_bounds__(256) void combine_k(
    const float* __restrict__ partial, float* __restrict__ out)
{
  const int idx = blockIdx.x * 256 + threadIdx.x;    // float4 index
  const int t = idx >> 9;                            // H/4 = 512 per row
  const int c = idx & 511;
  float4 s; s.x = 0.f; s.y = 0.f; s.z = 0.f; s.w = 0.f;
#pragma unroll
  for (int k = 0; k < TOPK; ++k) {
    const float4 v = *(const float4*)(partial + (size_t)(t * TOPK + k) * H_ + c * 4);
    s.x += v.x; s.y += v.y; s.z += v.z; s.w += v.w;
  }
  *(float4*)(out + (size_t)t * H_ + c * 4) = s;
}

// ---------------------------------------------------------------------------
extern "C" void kernel_launch(void* const* d_in, const int* in_sizes, int n_in,
                              void* d_out, int out_size, void* d_ws, size_t ws_size,
                              hipStream_t stream)
{
  const float* x  = (const float*)d_in[0];
  const float* rw = (const float*)d_in[1];
  const float* wg = (const float*)d_in[2];
  const float* wu = (const float*)d_in[3];
  const float* wd = (const float*)d_in[4];
  float* out = (float*)d_out;

  char* ws = (char*)d_ws;
  // workspace layout
  const size_t OFF_TOPW = 1024;                        // counts: 64 ints at 0
  const size_t OFF_ROWS = OFF_TOPW + (size_t)T_ * TOPK * 4;      // 33792
  const size_t OFF_HMID = OFF_ROWS + (size_t)E_ * CAP * 4;       // 295936
  const size_t OFF_PART = OFF_HMID + (size_t)T_ * TOPK * I_ * 2; // +16MB
  const size_t TOTAL    = OFF_PART + (size_t)T_ * TOPK * H_ * 4; // +64MB

  int*   counts = (int*)ws;
  float* topw   = (float*)(ws + OFF_TOPW);
  int*   rows   = (int*)(ws + OFF_ROWS);
  unsigned short* hmid = (unsigned short*)(ws + OFF_HMID);
  float* partial = (float*)(ws + OFF_PART);

  const int usePartial = (ws_size >= TOTAL) ? 1 : 0;

  hipMemsetAsync(counts, 0, E_ * sizeof(int), stream);
  router_k<<<T_, 256, 0, stream>>>(x, rw, topw, counts, rows);
  gateup_k<<<dim3(E_, I_ / TN), 256, 0, stream>>>(x, wg, wu, topw, counts, rows, hmid);
  if (usePartial) {
    down_k<<<dim3(E_, H_ / TN), 256, 0, stream>>>(hmid, wd, counts, rows, partial, 0);
    combine_k<<<(T_ * H_ / 4) / 256, 256, 0, stream>>>(partial, out);
  } else {
    hipMemsetAsync(out, 0, (size_t)out_size * sizeof(float), stream);
    down_k<<<dim3(E_, H_ / TN), 256, 0, stream>>>(hmid, wd, counts, rows, out, 1);
  }
}

// Round 2
// 1154.260 us; speedup vs baseline: 1.2163x; 1.2163x over previous
//
#include <hip/hip_runtime.h>
#include <hip/hip_bf16.h>
#include <math.h>

// Problem constants (B=2,S=512 -> T=1024)
#define T_    1024
#define H_    2048
#define E_    64
#define I_    1024
#define TOPK  8
#define CAP   1024        // max rows per expert (worst case all tokens)

// GEMM tiling
#define TM    64          // token rows per m-tile
#define TN    128         // output cols per block
#define BK    32          // k-chunk
#define LDK   (BK + 8)    // 80B rows -> 20-bank stride, conflict-free b128 reads

typedef __attribute__((ext_vector_type(8))) short  short8;
typedef __attribute__((ext_vector_type(8))) __bf16 bf16x8;
typedef __attribute__((ext_vector_type(4))) float  f32x4;

__device__ __forceinline__ unsigned short f2bf(float f) {
  unsigned int u = __float_as_uint(f);
  u += 0x7FFFu + ((u >> 16) & 1u);   // RNE
  return (unsigned short)(u >> 16);
}

// pack two fp32 -> two bf16 (round-half-up: same 0.5ulp bound as RNE) in 3 VALU
__device__ __forceinline__ unsigned int pack2bf(float lo, float hi) {
  const unsigned int a = __float_as_uint(hi) + 0x8000u;
  const unsigned int b = __float_as_uint(lo) + 0x8000u;
  return __builtin_amdgcn_perm(a, b, 0x07060302u);  // [b.hi16 | a.hi16<<16]
}

__device__ __forceinline__ uint2 pack4bf(float4 v) {
  uint2 p; p.x = pack2bf(v.x, v.y); p.y = pack2bf(v.z, v.w); return p;
}

__device__ __forceinline__ f32x4 mfma16(short8 a, short8 b, f32x4 c) {
  return __builtin_amdgcn_mfma_f32_16x16x32_bf16(
      __builtin_bit_cast(bf16x8, a), __builtin_bit_cast(bf16x8, b), c, 0, 0, 0);
}

// ---------------------------------------------------------------------------
// Kernel 1: router. One block per token. fp32 logits -> softmax -> top-8.
// ---------------------------------------------------------------------------
__global__ __launch_bounds__(256) void router_k(
    const float* __restrict__ x, const float* __restrict__ rw,
    float* __restrict__ topw, int* __restrict__ counts, int* __restrict__ rows)
{
  __shared__ float xs[H_];
  __shared__ float lg[E_];
  const int t   = blockIdx.x;
  const int tid = threadIdx.x;
  const float* xr = x + (size_t)t * H_;
  for (int q = tid; q < H_ / 4; q += 256)
    ((float4*)xs)[q] = ((const float4*)xr)[q];
  __syncthreads();

  const int w = tid >> 6, lane = tid & 63;
  for (int ee = 0; ee < E_ / 4; ++ee) {
    const int e = w * (E_ / 4) + ee;
    const float* wr = rw + (size_t)e * H_;
    float p = 0.f;
    for (int h = lane; h < H_; h += 64) p += xs[h] * wr[h];
    for (int off = 32; off; off >>= 1) p += __shfl_xor(p, off);
    if (lane == 0) lg[e] = p;
  }
  __syncthreads();

  if (w == 0) {
    const float logit = lg[lane];
    float mx = logit;
    for (int off = 32; off; off >>= 1) mx = fmaxf(mx, __shfl_xor(mx, off));
    const float ex = expf(logit - mx);
    float sum = ex;
    for (int off = 32; off; off >>= 1) sum += __shfl_xor(sum, off);
    float p = ex / sum;
    for (int k = 0; k < TOPK; ++k) {
      float m = p; int mi = lane;
      for (int off = 32; off; off >>= 1) {
        const float om = __shfl_xor(m, off);
        const int   oi = __shfl_xor(mi, off);
        if (om > m || (om == m && oi < mi)) { m = om; mi = oi; }
      }
      if (lane == 0) {
        const int r = t * TOPK + k;
        topw[r] = m;
        const int pos = atomicAdd(&counts[mi], 1);
        rows[mi * CAP + pos] = r;
      }
      if (lane == mi) p = -1.f;
    }
  }
}

// ---------------------------------------------------------------------------
// Kernel 2: gate/up GEMM per expert. grid=(E, I/TN). Reg-staged pipeline:
// per iter: ds_write(regs i) -> issue loads(i+1) -> barrier -> MFMA(i).
// Loads stay in flight across barrier + compute. One barrier/iter.
// ---------------------------------------------------------------------------
__global__ __launch_bounds__(256, 2) void gateup_k(
    const float* __restrict__ x, const float* __restrict__ wg,
    const float* __restrict__ wu, const float* __restrict__ topw,
    const int* __restrict__ counts, const int* __restrict__ rows,
    unsigned short* __restrict__ hmid)
{
  const int e  = blockIdx.x;
  const int n0 = blockIdx.y * TN;
  const int cnt = counts[e];
  if (cnt == 0) return;
  const int* erows = rows + e * CAP;

  __shared__ __align__(16) unsigned short Xs[2][TM][LDK];
  __shared__ __align__(16) unsigned short Gs[2][TN][LDK];
  __shared__ __align__(16) unsigned short Us[2][TN][LDK];

  const int tid = threadIdx.x;
  const int wid = tid >> 6, lane = tid & 63;
  const int wm = wid >> 1, wn = wid & 1;     // 2x2 waves: 32 rows x 64 cols each

  const float* wgE = wg + (size_t)e * I_ * H_;
  const float* wuE = wu + (size_t)e * I_ * H_;

  // weight staging: thread j-th chunk handles row (tid+j*256)>>3, seg (tid+j*256)&7
  const float* wgb[4]; const float* wub[4];
  int wrow[4], wsegb[4];
#pragma unroll
  for (int j = 0; j < 4; ++j) {
    const int q = tid + j * 256;
    wrow[j] = q >> 3; wsegb[j] = (q & 7) * 4;
    const size_t off = (size_t)(n0 + wrow[j]) * H_ + (size_t)(q & 7) * 4;
    wgb[j] = wgE + off; wub[j] = wuE + off;
  }
  // X staging: rows tid>>3 and (tid+256)>>3, seg tid&7
  const int xm0 = tid >> 3, xm1 = xm0 + 32;
  const int xsegb = (tid & 7) * 4;

  int tok0 = erows[(xm0 < cnt) ? xm0 : (cnt - 1)] >> 3;
  int tok1 = erows[(xm1 < cnt) ? xm1 : (cnt - 1)] >> 3;
  int ntok0 = tok0, ntok1 = tok1;

  float4 xr0, xr1, gr[4], ur[4];
  // prologue: issue loads for (m0=0, k0=0)
  xr0 = *(const float4*)(x + (size_t)tok0 * H_ + xsegb);
  xr1 = *(const float4*)(x + (size_t)tok1 * H_ + xsegb);
#pragma unroll
  for (int j = 0; j < 4; ++j) { gr[j] = *(const float4*)wgb[j]; ur[j] = *(const float4*)wub[j]; }

  int b = 0;
  for (int m0 = 0; m0 < cnt; m0 += TM) {
    f32x4 accg[2][4], accu[2][4];
#pragma unroll
    for (int i = 0; i < 2; ++i)
#pragma unroll
      for (int j = 0; j < 4; ++j)
#pragma unroll
        for (int q = 0; q < 4; ++q) { accg[i][j][q] = 0.f; accu[i][j][q] = 0.f; }

    for (int k0 = 0; k0 < H_; k0 += BK) {
      // ---- write phase: regs (this iter) -> LDS buf b
      *(uint2*)&Xs[b][xm0][xsegb] = pack4bf(xr0);
      *(uint2*)&Xs[b][xm1][xsegb] = pack4bf(xr1);
#pragma unroll
      for (int j = 0; j < 4; ++j) {
        *(uint2*)&Gs[b][wrow[j]][wsegb[j]] = pack4bf(gr[j]);
        *(uint2*)&Us[b][wrow[j]][wsegb[j]] = pack4bf(ur[j]);
      }
      // ---- prefetch next m-tile's row tokens early (once per m-tile)
      if (k0 == 0) {
        const int nm = m0 + TM;
        if (nm < cnt) {
          int i0 = nm + xm0; if (i0 >= cnt) i0 = cnt - 1;
          int i1 = nm + xm1; if (i1 >= cnt) i1 = cnt - 1;
          ntok0 = erows[i0] >> 3;
          ntok1 = erows[i1] >> 3;
        }
      }
      // ---- issue loads for next iter (stay in flight across barrier+MFMA)
      {
        int kn = k0 + BK;
        bool donext = true;
        if (kn >= H_) {
          if (m0 + TM < cnt) { kn = 0; tok0 = ntok0; tok1 = ntok1; }
          else donext = false;
        }
        if (donext) {
          xr0 = *(const float4*)(x + (size_t)tok0 * H_ + kn + xsegb);
          xr1 = *(const float4*)(x + (size_t)tok1 * H_ + kn + xsegb);
#pragma unroll
          for (int j = 0; j < 4; ++j) {
            gr[j] = *(const float4*)(wgb[j] + kn);
            ur[j] = *(const float4*)(wub[j] + kn);
          }
        }
      }
      __syncthreads();
      // ---- compute phase: consume buf b
      {
        const int ko  = (lane >> 4) * 8;
        const int ar0 = wm * 32 + (lane & 15);
        const short8 a0 = *(const short8*)&Xs[b][ar0][ko];
        const short8 a1 = *(const short8*)&Xs[b][ar0 + 16][ko];
#pragma unroll
        for (int ni = 0; ni < 4; ++ni) {
          const int col = wn * 64 + ni * 16 + (lane & 15);
          const short8 bg = *(const short8*)&Gs[b][col][ko];
          const short8 bu = *(const short8*)&Us[b][col][ko];
          accg[0][ni] = mfma16(a0, bg, accg[0][ni]);
          accg[1][ni] = mfma16(a1, bg, accg[1][ni]);
          accu[0][ni] = mfma16(a0, bu, accu[0][ni]);
          accu[1][ni] = mfma16(a1, bu, accu[1][ni]);
        }
      }
      b ^= 1;
    }
    // ---- epilogue: h = silu(g)*u*cw -> bf16 store (loads for next tile in flight)
#pragma unroll
    for (int mi = 0; mi < 2; ++mi)
#pragma unroll
      for (int ni = 0; ni < 4; ++ni)
#pragma unroll
        for (int j = 0; j < 4; ++j) {
          const int ml = wm * 32 + mi * 16 + (lane >> 4) * 4 + j;
          if (m0 + ml < cnt) {
            const int r = erows[m0 + ml];
            const float cw = topw[r];
            const float g = accg[mi][ni][j], u = accu[mi][ni][j];
            const float h = g / (1.f + __expf(-g)) * u * cw;
            hmid[(size_t)r * I_ + n0 + wn * 64 + ni * 16 + (lane & 15)] = f2bf(h);
          }
        }
  }
}

// ---------------------------------------------------------------------------
// Kernel 3: down GEMM per expert. grid=(E, H/TN). Same pipeline structure.
// ---------------------------------------------------------------------------
__global__ __launch_bounds__(256, 3) void down_k(
    const unsigned short* __restrict__ hmid, const float* __restrict__ wd,
    const int* __restrict__ counts, const int* __restrict__ rows,
    float* __restrict__ outp, const int atomicMode)
{
  const int e  = blockIdx.x;
  const int n0 = blockIdx.y * TN;
  const int cnt = counts[e];
  if (cnt == 0) return;
  const int* erows = rows + e * CAP;

  __shared__ __align__(16) unsigned short As[2][TM][LDK];
  __shared__ __align__(16) unsigned short Ws[2][TN][LDK];

  const int tid = threadIdx.x;
  const int wid = tid >> 6, lane = tid & 63;
  const int wm = wid >> 1, wn = wid & 1;

  const float* wdE = wd + (size_t)e * H_ * I_;

  const float* wb[4];
  int wrow[4], wsegb[4];
#pragma unroll
  for (int j = 0; j < 4; ++j) {
    const int q = tid + j * 256;
    wrow[j] = q >> 3; wsegb[j] = (q & 7) * 4;
    wb[j] = wdE + (size_t)(n0 + wrow[j]) * I_ + (size_t)(q & 7) * 4;
  }
  // A staging: row tid>>2, seg tid&3 (8 bf16 = 16B each)
  const int am = tid >> 2;
  const int asegb = (tid & 3) * 8;

  int atok = erows[(am < cnt) ? am : (cnt - 1)];
  int natok = atok;

  uint4 arv; float4 wr[4];
  arv = *(const uint4*)(hmid + (size_t)atok * I_ + asegb);
#pragma unroll
  for (int j = 0; j < 4; ++j) wr[j] = *(const float4*)wb[j];

  int b = 0;
  for (int m0 = 0; m0 < cnt; m0 += TM) {
    f32x4 acc[2][4];
#pragma unroll
    for (int i = 0; i < 2; ++i)
#pragma unroll
      for (int j = 0; j < 4; ++j)
#pragma unroll
        for (int q = 0; q < 4; ++q) acc[i][j][q] = 0.f;

    for (int k0 = 0; k0 < I_; k0 += BK) {
      // write phase
      *(uint4*)&As[b][am][asegb] = arv;
#pragma unroll
      for (int j = 0; j < 4; ++j)
        *(uint2*)&Ws[b][wrow[j]][wsegb[j]] = pack4bf(wr[j]);

      if (k0 == 0) {
        const int nm = m0 + TM;
        if (nm < cnt) {
          int i0 = nm + am; if (i0 >= cnt) i0 = cnt - 1;
          natok = erows[i0];
        }
      }
      {
        int kn = k0 + BK;
        bool donext = true;
        if (kn >= I_) {
          if (m0 + TM < cnt) { kn = 0; atok = natok; }
          else donext = false;
        }
        if (donext) {
          arv = *(const uint4*)(hmid + (size_t)atok * I_ + kn + asegb);
#pragma unroll
          for (int j = 0; j < 4; ++j) wr[j] = *(const float4*)(wb[j] + kn);
        }
      }
      __syncthreads();
      // compute phase
      {
        const int ko  = (lane >> 4) * 8;
        const int ar0 = wm * 32 + (lane & 15);
        const short8 a0 = *(const short8*)&As[b][ar0][ko];
        const short8 a1 = *(const short8*)&As[b][ar0 + 16][ko];
#pragma unroll
        for (int ni = 0; ni < 4; ++ni) {
          const short8 bw = *(const short8*)&Ws[b][wn * 64 + ni * 16 + (lane & 15)][ko];
          acc[0][ni] = mfma16(a0, bw, acc[0][ni]);
          acc[1][ni] = mfma16(a1, bw, acc[1][ni]);
        }
      }
      b ^= 1;
    }
#pragma unroll
    for (int mi = 0; mi < 2; ++mi)
#pragma unroll
      for (int ni = 0; ni < 4; ++ni)
#pragma unroll
        for (int j = 0; j < 4; ++j) {
          const int ml = wm * 32 + mi * 16 + (lane >> 4) * 4 + j;
          if (m0 + ml < cnt) {
            const int r = erows[m0 + ml];
            const int col = n0 + wn * 64 + ni * 16 + (lane & 15);
            if (atomicMode) atomicAdd(&outp[(size_t)(r >> 3) * H_ + col], acc[mi][ni][j]);
            else            outp[(size_t)r * H_ + col] = acc[mi][ni][j];
          }
        }
  }
}

// ---------------------------------------------------------------------------
// Kernel 4: combine partials over k=0..7 (deterministic fixed-order sum)
// ---------------------------------------------------------------------------
__global__ __launch_bounds__(256) void combine_k(
    const float* __restrict__ partial, float* __restrict__ out)
{
  const int idx = blockIdx.x * 256 + threadIdx.x;    // float4 index
  const int t = idx >> 9;                            // H/4 = 512 per row
  const int c = idx & 511;
  float4 s; s.x = 0.f; s.y = 0.f; s.z = 0.f; s.w = 0.f;
#pragma unroll
  for (int k = 0; k < TOPK; ++k) {
    const float4 v = *(const float4*)(partial + (size_t)(t * TOPK + k) * H_ + c * 4);
    s.x += v.x; s.y += v.y; s.z += v.z; s.w += v.w;
  }
  *(float4*)(out + (size_t)t * H_ + c * 4) = s;
}

// ---------------------------------------------------------------------------
extern "C" void kernel_launch(void* const* d_in, const int* in_sizes, int n_in,
                              void* d_out, int out_size, void* d_ws, size_t ws_size,
                              hipStream_t stream)
{
  const float* x  = (const float*)d_in[0];
  const float* rw = (const float*)d_in[1];
  const float* wg = (const float*)d_in[2];
  const float* wu = (const float*)d_in[3];
  const float* wd = (const float*)d_in[4];
  float* out = (float*)d_out;

  char* ws = (char*)d_ws;
  const size_t OFF_TOPW = 1024;
  const size_t OFF_ROWS = OFF_TOPW + (size_t)T_ * TOPK * 4;
  const size_t OFF_HMID = OFF_ROWS + (size_t)E_ * CAP * 4;
  const size_t OFF_PART = OFF_HMID + (size_t)T_ * TOPK * I_ * 2;
  const size_t TOTAL    = OFF_PART + (size_t)T_ * TOPK * H_ * 4;

  int*   counts = (int*)ws;
  float* topw   = (float*)(ws + OFF_TOPW);
  int*   rows   = (int*)(ws + OFF_ROWS);
  unsigned short* hmid = (unsigned short*)(ws + OFF_HMID);
  float* partial = (float*)(ws + OFF_PART);

  const int usePartial = (ws_size >= TOTAL) ? 1 : 0;

  hipMemsetAsync(counts, 0, E_ * sizeof(int), stream);
  router_k<<<T_, 256, 0, stream>>>(x, rw, topw, counts, rows);
  gateup_k<<<dim3(E_, I_ / TN), 256, 0, stream>>>(x, wg, wu, topw, counts, rows, hmid);
  if (usePartial) {
    down_k<<<dim3(E_, H_ / TN), 256, 0, stream>>>(hmid, wd, counts, rows, partial, 0);
    combine_k<<<(T_ * H_ / 4) / 256, 256, 0, stream>>>(partial, out);
  } else {
    hipMemsetAsync(out, 0, (size_t)out_size * sizeof(float), stream);
    down_k<<<dim3(E_, H_ / TN), 256, 0, stream>>>(hmid, wd, counts, rows, out, 1);
  }
}

// Round 3
// 671.986 us; speedup vs baseline: 2.0892x; 1.7177x over previous
//
#include <hip/hip_runtime.h>
#include <hip/hip_bf16.h>
#include <math.h>

// Problem constants (B=2,S=512 -> T=1024)
#define T_    1024
#define H_    2048
#define E_    64
#define I_    1024
#define TOPK  8
#define CAP   1024        // max rows per expert (worst case)

// GEMM tiling (both gemms): 192 token-rows x 64 out-cols, K-chunk 32
#define GTM   192
#define GTN   64
#define GBK   32

typedef __attribute__((ext_vector_type(8))) short  short8;
typedef __attribute__((ext_vector_type(8))) __bf16 bf16x8;
typedef __attribute__((ext_vector_type(4))) float  f32x4;

__device__ __forceinline__ unsigned short f2bf(float f) {
  unsigned int u = __float_as_uint(f);
  u += 0x7FFFu + ((u >> 16) & 1u);   // RNE
  return (unsigned short)(u >> 16);
}

// pack two fp32 -> [bf16(lo) | bf16(hi)<<16] (round-half-up, 0.5ulp)
__device__ __forceinline__ unsigned int pack2bf(float lo, float hi) {
  const unsigned int a = __float_as_uint(hi) + 0x8000u;
  const unsigned int b = __float_as_uint(lo) + 0x8000u;
  return __builtin_amdgcn_perm(a, b, 0x07060302u);
}

__device__ __forceinline__ f32x4 mfma16(short8 a, short8 b, f32x4 c) {
  return __builtin_amdgcn_mfma_f32_16x16x32_bf16(
      __builtin_bit_cast(bf16x8, a), __builtin_bit_cast(bf16x8, b), c, 0, 0, 0);
}

// async global->LDS, 16B per lane. LDS dest must be wave-uniform base + lane*16.
__device__ __forceinline__ void gload16(const void* g, void* lds) {
  auto gp = reinterpret_cast<const __attribute__((address_space(1))) unsigned int*>(
      reinterpret_cast<uintptr_t>(g));
  auto lp = reinterpret_cast<__attribute__((address_space(3))) unsigned int*>(
      static_cast<unsigned int>(reinterpret_cast<uintptr_t>(lds)));
  __builtin_amdgcn_global_load_lds(gp, lp, 16, 0, 0);
}

// build a bf16x8 fragment from two float4s (8 consecutive k-elements)
__device__ __forceinline__ short8 cvt_frag(float4 lo, float4 hi) {
  uint4 u;
  u.x = pack2bf(lo.x, lo.y); u.y = pack2bf(lo.z, lo.w);
  u.z = pack2bf(hi.x, hi.y); u.w = pack2bf(hi.z, hi.w);
  return __builtin_bit_cast(short8, u);
}

// ---------------------------------------------------------------------------
// Kernel 1: router. One block per token. fp32 logits -> softmax -> top-8.
// ---------------------------------------------------------------------------
__global__ __launch_bounds__(256) void router_k(
    const float* __restrict__ x, const float* __restrict__ rw,
    float* __restrict__ topw, int* __restrict__ counts, int* __restrict__ rows)
{
  __shared__ float xs[H_];
  __shared__ float lg[E_];
  const int t   = blockIdx.x;
  const int tid = threadIdx.x;
  const float* xr = x + (size_t)t * H_;
  for (int q = tid; q < H_ / 4; q += 256)
    ((float4*)xs)[q] = ((const float4*)xr)[q];
  __syncthreads();

  const int w = tid >> 6, lane = tid & 63;
  for (int ee = 0; ee < E_ / 4; ++ee) {
    const int e = w * (E_ / 4) + ee;
    const float* wr = rw + (size_t)e * H_;
    float p = 0.f;
    for (int h = lane; h < H_; h += 64) p += xs[h] * wr[h];
    for (int off = 32; off; off >>= 1) p += __shfl_xor(p, off);
    if (lane == 0) lg[e] = p;
  }
  __syncthreads();

  if (w == 0) {
    const float logit = lg[lane];
    float mx = logit;
    for (int off = 32; off; off >>= 1) mx = fmaxf(mx, __shfl_xor(mx, off));
    const float ex = expf(logit - mx);
    float sum = ex;
    for (int off = 32; off; off >>= 1) sum += __shfl_xor(sum, off);
    float p = ex / sum;
    for (int k = 0; k < TOPK; ++k) {
      float m = p; int mi = lane;
      for (int off = 32; off; off >>= 1) {
        const float om = __shfl_xor(m, off);
        const int   oi = __shfl_xor(mi, off);
        if (om > m || (om == m && oi < mi)) { m = om; mi = oi; }
      }
      if (lane == 0) {
        const int r = t * TOPK + k;
        topw[r] = m;
        const int pos = atomicAdd(&counts[mi], 1);
        rows[mi * CAP + pos] = r;
      }
      if (lane == mi) p = -1.f;
    }
  }
}

// ---------------------------------------------------------------------------
// Kernel 2: gate/up GEMM. grid=(E, I/64), 512 threads (8 waves: 4m x 2n).
// TM=192 covers all tokens of an expert in one pass -> weights fetched once.
// Staging via global_load_lds: A fp32 gathered from x, B fp32 (wg/wu);
// XOR-swizzled source addresses, linear LDS dest, XOR on read. cvt on read.
// ---------------------------------------------------------------------------
__global__ __launch_bounds__(512, 4) void gateup_k(
    const float* __restrict__ x, const float* __restrict__ wg,
    const float* __restrict__ wu, const float* __restrict__ topw,
    const int* __restrict__ counts, const int* __restrict__ rows,
    unsigned short* __restrict__ hmid)
{
  const int e  = blockIdx.x;
  const int n0 = blockIdx.y * GTN;
  const int cnt = counts[e];
  if (cnt == 0) return;
  const int* erows = rows + e * CAP;

  __shared__ __align__(16) float Al [GTM][GBK];   // 24KB, rows 128B, 8 chunks
  __shared__ __align__(16) float Bgl[GTN][GBK];   // 8KB
  __shared__ __align__(16) float Bul[GTN][GBK];   // 8KB

  const int tid  = threadIdx.x;
  const int wid  = tid >> 6, lane = tid & 63;
  const int wm   = wid >> 1, wn = wid & 1;        // 4x2 waves: 48 rows x 32 cols

  const float* wgE = wg + (size_t)e * I_ * H_ + (size_t)n0 * H_;
  const float* wuE = wu + (size_t)e * I_ * H_ + (size_t)n0 * H_;

  // ---- staging geometry (linear LDS dest; source chunk XOR-swizzled) ----
  // A round q: lds byte = q*8192 + wid*1024 + lane*16 -> row=q*64+wid*8+(lane>>3), phys=lane&7
  int arow[3], acoff[3];
#pragma unroll
  for (int q = 0; q < 3; ++q) {
    const int row = q * 64 + wid * 8 + (lane >> 3);
    arow[q]  = row;
    acoff[q] = ((lane & 7) ^ (row & 7)) * 4;      // float offset within k-slice
  }
  const int brow  = wid * 8 + (lane >> 3);
  const int bcoff = ((lane & 7) ^ (brow & 7)) * 4;

  char* AlB = (char*)Al; char* BgB = (char*)Bgl; char* BuB = (char*)Bul;
  const int ldsLane = wid * 1024 + lane * 16;

  // ---- fragment LDS offsets (float units), constant across k ----
  int aoff[3][2], boff[2][2];
  const int h = lane >> 4;
#pragma unroll
  for (int mi = 0; mi < 3; ++mi) {
    const int r = wm * 48 + mi * 16 + (lane & 15);
    aoff[mi][0] = r * GBK + (((2*h    ) ^ (r & 7)) * 4);
    aoff[mi][1] = r * GBK + (((2*h + 1) ^ (r & 7)) * 4);
  }
#pragma unroll
  for (int ni = 0; ni < 2; ++ni) {
    const int r = wn * 32 + ni * 16 + (lane & 15);
    boff[ni][0] = r * GBK + (((2*h    ) ^ (r & 7)) * 4);
    boff[ni][1] = r * GBK + (((2*h + 1) ^ (r & 7)) * 4);
  }

  for (int m0 = 0; m0 < cnt; m0 += GTM) {
    // per-m-tile A source pointers (per-lane gather from x)
    const float* pa[3];
#pragma unroll
    for (int q = 0; q < 3; ++q) {
      int idx = m0 + arow[q]; if (idx >= cnt) idx = cnt - 1;
      pa[q] = x + (size_t)(erows[idx] >> 3) * H_ + acoff[q];
    }
    const float* pg = wgE + (size_t)brow * H_ + bcoff;
    const float* pu = wuE + (size_t)brow * H_ + bcoff;

    f32x4 accg[3][2], accu[3][2];
#pragma unroll
    for (int i = 0; i < 3; ++i)
#pragma unroll
      for (int j = 0; j < 2; ++j)
#pragma unroll
        for (int q = 0; q < 4; ++q) { accg[i][j][q] = 0.f; accu[i][j][q] = 0.f; }

    for (int k0 = 0; k0 < H_; k0 += GBK) {
      __syncthreads();                      // prev-iter reads done
      gload16(pa[0], AlB +     0 + ldsLane);
      gload16(pa[1], AlB +  8192 + ldsLane);
      gload16(pa[2], AlB + 16384 + ldsLane);
      gload16(pg,    BgB + ldsLane);
      gload16(pu,    BuB + ldsLane);
      pa[0] += GBK; pa[1] += GBK; pa[2] += GBK; pg += GBK; pu += GBK;
      __syncthreads();                      // vmcnt drained -> tile visible

      short8 af[3];
#pragma unroll
      for (int mi = 0; mi < 3; ++mi) {
        const float4 lo = *(const float4*)&((const float*)Al)[aoff[mi][0]];
        const float4 hi = *(const float4*)&((const float*)Al)[aoff[mi][1]];
        af[mi] = cvt_frag(lo, hi);
      }
#pragma unroll
      for (int ni = 0; ni < 2; ++ni) {
        const float4 glo = *(const float4*)&((const float*)Bgl)[boff[ni][0]];
        const float4 ghi = *(const float4*)&((const float*)Bgl)[boff[ni][1]];
        const short8 bg = cvt_frag(glo, ghi);
        const float4 ulo = *(const float4*)&((const float*)Bul)[boff[ni][0]];
        const float4 uhi = *(const float4*)&((const float*)Bul)[boff[ni][1]];
        const short8 bu = cvt_frag(ulo, uhi);
#pragma unroll
        for (int mi = 0; mi < 3; ++mi) {
          accg[mi][ni] = mfma16(af[mi], bg, accg[mi][ni]);
          accu[mi][ni] = mfma16(af[mi], bu, accu[mi][ni]);
        }
      }
    }
    // epilogue: h = silu(g)*u*cw -> bf16
#pragma unroll
    for (int mi = 0; mi < 3; ++mi)
#pragma unroll
      for (int ni = 0; ni < 2; ++ni)
#pragma unroll
        for (int j = 0; j < 4; ++j) {
          const int ml = wm * 48 + mi * 16 + (lane >> 4) * 4 + j;
          if (m0 + ml < cnt) {
            const int r = erows[m0 + ml];
            const float cw = topw[r];
            const float g = accg[mi][ni][j], uu = accu[mi][ni][j];
            const float hv = g / (1.f + __expf(-g)) * uu * cw;
            hmid[(size_t)r * I_ + n0 + wn * 32 + ni * 16 + (lane & 15)] = f2bf(hv);
          }
        }
  }
}

// ---------------------------------------------------------------------------
// Kernel 3: down GEMM. grid=(E, H/64), 512 threads. A = hmid (bf16, gathered),
// B = w_down fp32. Same structure.
// ---------------------------------------------------------------------------
__global__ __launch_bounds__(512, 4) void down_k(
    const unsigned short* __restrict__ hmid, const float* __restrict__ wd,
    const int* __restrict__ counts, const int* __restrict__ rows,
    float* __restrict__ outp, const int atomicMode)
{
  const int e  = blockIdx.x;
  const int n0 = blockIdx.y * GTN;
  const int cnt = counts[e];
  if (cnt == 0) return;
  const int* erows = rows + e * CAP;

  __shared__ __align__(16) unsigned short Al[GTM][GBK];  // 12KB, rows 64B, 4 chunks
  __shared__ __align__(16) float          Bl[GTN][GBK];  // 8KB

  const int tid  = threadIdx.x;
  const int wid  = tid >> 6, lane = tid & 63;
  const int wm   = wid >> 1, wn = wid & 1;

  const float* wdE = wd + (size_t)e * H_ * I_ + (size_t)n0 * I_;

  // A staging: round0 rows 0..127 (all waves), round1 rows 128..191 (waves 0-3)
  const int arow0 = wid * 16 + (lane >> 2);
  const int arow1 = 128 + arow0;
  const int ac0 = (((lane & 3) ^ ((arow0 >> 1) & 3))) * 8;  // ushort offset
  const int ac1 = (((lane & 3) ^ ((arow1 >> 1) & 3))) * 8;
  const int brow  = wid * 8 + (lane >> 3);
  const int bcoff = ((lane & 7) ^ (brow & 7)) * 4;

  char* AlB = (char*)Al; char* BlB = (char*)Bl;
  const int ldsLane = wid * 1024 + lane * 16;

  int aoff[3], boff[2][2];
  const int h = lane >> 4;
#pragma unroll
  for (int mi = 0; mi < 3; ++mi) {
    const int r = wm * 48 + mi * 16 + (lane & 15);
    aoff[mi] = r * GBK + ((h ^ ((r >> 1) & 3)) * 8);        // ushort units
  }
#pragma unroll
  for (int ni = 0; ni < 2; ++ni) {
    const int r = wn * 32 + ni * 16 + (lane & 15);
    boff[ni][0] = r * GBK + (((2*h    ) ^ (r & 7)) * 4);
    boff[ni][1] = r * GBK + (((2*h + 1) ^ (r & 7)) * 4);
  }

  for (int m0 = 0; m0 < cnt; m0 += GTM) {
    int i0 = m0 + arow0; if (i0 >= cnt) i0 = cnt - 1;
    int i1 = m0 + arow1; if (i1 >= cnt) i1 = cnt - 1;
    const unsigned short* pa0 = hmid + (size_t)erows[i0] * I_ + ac0;
    const unsigned short* pa1 = hmid + (size_t)erows[i1] * I_ + ac1;
    const float* pb = wdE + (size_t)brow * I_ + bcoff;

    f32x4 acc[3][2];
#pragma unroll
    for (int i = 0; i < 3; ++i)
#pragma unroll
      for (int j = 0; j < 2; ++j)
#pragma unroll
        for (int q = 0; q < 4; ++q) acc[i][j][q] = 0.f;

    for (int k0 = 0; k0 < I_; k0 += GBK) {
      __syncthreads();
      gload16(pa0, AlB + ldsLane);
      if (wid < 4) gload16(pa1, AlB + 8192 + ldsLane);
      gload16(pb, BlB + ldsLane);
      pa0 += GBK; pa1 += GBK; pb += GBK;
      __syncthreads();

      short8 af[3];
#pragma unroll
      for (int mi = 0; mi < 3; ++mi)
        af[mi] = *(const short8*)&((const unsigned short*)Al)[aoff[mi]];
#pragma unroll
      for (int ni = 0; ni < 2; ++ni) {
        const float4 blo = *(const float4*)&((const float*)Bl)[boff[ni][0]];
        const float4 bhi = *(const float4*)&((const float*)Bl)[boff[ni][1]];
        const short8 bw = cvt_frag(blo, bhi);
#pragma unroll
        for (int mi = 0; mi < 3; ++mi)
          acc[mi][ni] = mfma16(af[mi], bw, acc[mi][ni]);
      }
    }
#pragma unroll
    for (int mi = 0; mi < 3; ++mi)
#pragma unroll
      for (int ni = 0; ni < 2; ++ni)
#pragma unroll
        for (int j = 0; j < 4; ++j) {
          const int ml = wm * 48 + mi * 16 + (lane >> 4) * 4 + j;
          if (m0 + ml < cnt) {
            const int r = erows[m0 + ml];
            const int col = n0 + wn * 32 + ni * 16 + (lane & 15);
            if (atomicMode) atomicAdd(&outp[(size_t)(r >> 3) * H_ + col], acc[mi][ni][j]);
            else            outp[(size_t)r * H_ + col] = acc[mi][ni][j];
          }
        }
  }
}

// ---------------------------------------------------------------------------
// Kernel 4: combine partials over k=0..7 (deterministic fixed-order sum)
// ---------------------------------------------------------------------------
__global__ __launch_bounds__(256) void combine_k(
    const float* __restrict__ partial, float* __restrict__ out)
{
  const int idx = blockIdx.x * 256 + threadIdx.x;
  const int t = idx >> 9;
  const int c = idx & 511;
  float4 s; s.x = 0.f; s.y = 0.f; s.z = 0.f; s.w = 0.f;
#pragma unroll
  for (int k = 0; k < TOPK; ++k) {
    const float4 v = *(const float4*)(partial + (size_t)(t * TOPK + k) * H_ + c * 4);
    s.x += v.x; s.y += v.y; s.z += v.z; s.w += v.w;
  }
  *(float4*)(out + (size_t)t * H_ + c * 4) = s;
}

// ---------------------------------------------------------------------------
extern "C" void kernel_launch(void* const* d_in, const int* in_sizes, int n_in,
                              void* d_out, int out_size, void* d_ws, size_t ws_size,
                              hipStream_t stream)
{
  const float* x  = (const float*)d_in[0];
  const float* rw = (const float*)d_in[1];
  const float* wg = (const float*)d_in[2];
  const float* wu = (const float*)d_in[3];
  const float* wd = (const float*)d_in[4];
  float* out = (float*)d_out;

  char* ws = (char*)d_ws;
  const size_t OFF_TOPW = 1024;
  const size_t OFF_ROWS = OFF_TOPW + (size_t)T_ * TOPK * 4;
  const size_t OFF_HMID = OFF_ROWS + (size_t)E_ * CAP * 4;
  const size_t OFF_PART = OFF_HMID + (size_t)T_ * TOPK * I_ * 2;
  const size_t TOTAL    = OFF_PART + (size_t)T_ * TOPK * H_ * 4;

  int*   counts = (int*)ws;
  float* topw   = (float*)(ws + OFF_TOPW);
  int*   rows   = (int*)(ws + OFF_ROWS);
  unsigned short* hmid = (unsigned short*)(ws + OFF_HMID);
  float* partial = (float*)(ws + OFF_PART);

  const int usePartial = (ws_size >= TOTAL) ? 1 : 0;

  hipMemsetAsync(counts, 0, E_ * sizeof(int), stream);
  router_k<<<T_, 256, 0, stream>>>(x, rw, topw, counts, rows);
  gateup_k<<<dim3(E_, I_ / GTN), 512, 0, stream>>>(x, wg, wu, topw, counts, rows, hmid);
  if (usePartial) {
    down_k<<<dim3(E_, H_ / GTN), 512, 0, stream>>>(hmid, wd, counts, rows, partial, 0);
    combine_k<<<(T_ * H_ / 4) / 256, 256, 0, stream>>>(partial, out);
  } else {
    hipMemsetAsync(out, 0, (size_t)out_size * sizeof(float), stream);
    down_k<<<dim3(E_, H_ / GTN), 512, 0, stream>>>(hmid, wd, counts, rows, out, 1);
  }
}